// Round 7
// baseline (2490.262 us; speedup 1.0000x reference)
//
#include <hip/hip_runtime.h>
#include <hip/hip_bf16.h>

typedef unsigned short u16;
typedef unsigned int u32;
typedef __bf16 bf16t;
typedef bf16t bf16x8 __attribute__((ext_vector_type(8)));
typedef float f32x4 __attribute__((ext_vector_type(4)));

constexpr int S_   = 2048;
constexpr int D_   = 2048;
constexpr int H_   = 16;
constexpr int DH_  = 128;
constexpr int L_   = 2;
constexpr int DFF_ = 8192;
constexpr int V_   = 32000;
constexpr int R_   = 8;

#define MFMA16(a, b, c) __builtin_amdgcn_mfma_f32_16x16x32_bf16(a, b, c, 0, 0, 0)

__constant__ float c_nf4[16] = {
  -1.0f, -0.6961928009986877f, -0.5250730514526367f, -0.39491748809814453f,
  -0.28444138169288635f, -0.18477343022823334f, -0.09105003625154495f, 0.0f,
  0.07958029955625534f, 0.16093020141124725f, 0.24611230194568634f,
  0.33791524171829224f, 0.44070982933044434f, 0.5626170039176941f,
  0.7229568362236023f, 1.0f };

__device__ __forceinline__ u16 f2bf(float f) {
  union { float f; u32 u; } v; v.f = f;
  u32 r = v.u + 0x7fffu + ((v.u >> 16) & 1u);
  return (u16)(r >> 16);
}
__device__ __forceinline__ float bf2f(u16 h) {
  union { u32 u; float f; } v; v.u = ((u32)h) << 16; return v.f;
}

// ---------------- embedding gather ----------------
__global__ __launch_bounds__(256) void k_gather(const int* __restrict__ ids,
                                                const float* __restrict__ emb,
                                                float* __restrict__ h) {
  int t = blockIdx.x * 256 + threadIdx.x;
  int s = t >> 11;
  int d = t & 2047;
  h[t] = emb[(size_t)ids[s] * D_ + d];
}

// ---------------- rmsnorm f32 -> bf16 ----------------
__global__ __launch_bounds__(256) void k_rmsnorm(const float* __restrict__ in,
                                                 const float* __restrict__ w,
                                                 u16* __restrict__ out) {
  int s = blockIdx.x;
  const float* x = in + (size_t)s * D_;
  float ss = 0.f;
  for (int d = threadIdx.x; d < D_; d += 256) { float v = x[d]; ss += v * v; }
#pragma unroll
  for (int m = 1; m < 64; m <<= 1) ss += __shfl_xor(ss, m, 64);
  __shared__ float sh[4];
  if ((threadIdx.x & 63) == 0) sh[threadIdx.x >> 6] = ss;
  __syncthreads();
  ss = sh[0] + sh[1] + sh[2] + sh[3];
  float sc = rsqrtf(ss * (1.0f / D_) + 1e-6f);
  u16* o = out + (size_t)s * D_;
  for (int d = threadIdx.x; d < D_; d += 256) o[d] = f2bf(x[d] * sc * w[d]);
}

// ---------------- NF4 dequant ----------------
__global__ __launch_bounds__(256) void k_dequant(const int* __restrict__ idx,
                                                 const float* __restrict__ scale,
                                                 u16* __restrict__ out, int kshift) {
  size_t t = (size_t)blockIdx.x * 256 + threadIdx.x;
  size_t e = t * 8;
  int k = (int)(e & ((1u << kshift) - 1));
  size_t n = e >> kshift;
  float s = scale[(n << (kshift - 6)) + (k >> 6)];
  int4 i0 = *(const int4*)(idx + e);
  int4 i1 = *(const int4*)(idx + e + 4);
  uint4 o;
  o.x = (u32)f2bf(c_nf4[i0.x] * s) | ((u32)f2bf(c_nf4[i0.y] * s) << 16);
  o.y = (u32)f2bf(c_nf4[i0.z] * s) | ((u32)f2bf(c_nf4[i0.w] * s) << 16);
  o.z = (u32)f2bf(c_nf4[i1.x] * s) | ((u32)f2bf(c_nf4[i1.y] * s) << 16);
  o.w = (u32)f2bf(c_nf4[i1.z] * s) | ((u32)f2bf(c_nf4[i1.w] * s) << 16);
  *(uint4*)(out + e) = o;
}

// ---------------- f32 -> bf16 convert (emb) ----------------
__global__ __launch_bounds__(256) void k_f2b(const float* __restrict__ src,
                                             u16* __restrict__ dst) {
  size_t e = ((size_t)blockIdx.x * 256 + threadIdx.x) * 8;
  float4 f0 = *(const float4*)(src + e);
  float4 f1 = *(const float4*)(src + e + 4);
  uint4 o;
  o.x = (u32)f2bf(f0.x) | ((u32)f2bf(f0.y) << 16);
  o.y = (u32)f2bf(f0.z) | ((u32)f2bf(f0.w) << 16);
  o.z = (u32)f2bf(f1.x) | ((u32)f2bf(f1.y) << 16);
  o.w = (u32)f2bf(f1.z) | ((u32)f2bf(f1.w) << 16);
  *(uint4*)(dst + e) = o;
}

// ---------------- transpose-convert: emb f32 [V,D] -> embT bf16 [D,V] ----------
__global__ __launch_bounds__(256) void k_transpose(const float* __restrict__ src,
                                                   u16* __restrict__ dst) {
  __shared__ u16 tile[64][65];
  int v0 = blockIdx.x * 64, d0 = blockIdx.y * 64;
  int tid = threadIdx.x;
  int rr = tid >> 4, cc = (tid & 15) * 4;
#pragma unroll
  for (int j = 0; j < 4; ++j) {
    int r = j * 16 + rr;
    float4 f = *(const float4*)(src + (size_t)(v0 + r) * D_ + d0 + cc);
    tile[r][cc + 0] = f2bf(f.x); tile[r][cc + 1] = f2bf(f.y);
    tile[r][cc + 2] = f2bf(f.z); tile[r][cc + 3] = f2bf(f.w);
  }
  __syncthreads();
#pragma unroll
  for (int j = 0; j < 4; ++j) {
    int r = j * 16 + rr;
    ushort4 w;
    w.x = tile[cc + 0][r]; w.y = tile[cc + 1][r];
    w.z = tile[cc + 2][r]; w.w = tile[cc + 3][r];
    *(ushort4*)(dst + (size_t)(d0 + r) * V_ + v0 + cc) = w;
  }
}

// ======== 256x256 pipelined MFMA GEMM, reads issued one phase early ========
// 512 thr = 8 waves (2M x 4N), BK=64, LDS 128 KiB double-buffered.
// Fragments A0/A1/B0/B1 in separate regs; each phase issues the NEXT phase's
// ds_reads before its barrier so they drain under the current MFMA burst.
// p1{rd B1; Q00=A0.B0} p2{rd A1; Q01=A0.B1} p3{stage t+2 B; Q11=A1.B1}
// p4{stage t+2 A; Q10=A1.B0; vmcnt(8); bar; rd next A0,B0}. One drain/tile.
enum { OUT_F32 = 0, OUT_F32_ACC = 1, OUT_BF16 = 2 };

template<int OUTMODE>
__global__ __launch_bounds__(512, 2) void k_gemm256(const u16* __restrict__ A, int lda,
                                                    const u16* __restrict__ B, int ldb,
                                                    void* __restrict__ Cv, int ldc,
                                                    int Kc, size_t zstride) {
  __shared__ u16 As[2][256][64];
  __shared__ u16 Bs[2][256][64];
  const int tid = threadIdx.x;
  const int lane = tid & 63, w = tid >> 6;
  const int wr = w >> 2, wc = w & 3;
  const int g = (lane >> 4), l15 = lane & 15, sl7 = lane & 7;

  // XCD swizzle, N-major within chunk: all gy M-blocks of an N-panel on one XCD
  const int gx = gridDim.x, gy = gridDim.y;
  const int cpx = (gx * gy) >> 3;
  int d = blockIdx.y * gx + blockIdx.x;
  int swz = (d & 7) * cpx + (d >> 3);
  const int m0 = (swz % gy) * 256;
  const int n0 = (swz / gy) * 256;

  A += (size_t)blockIdx.z * Kc;
  B += (size_t)blockIdx.z * Kc;
  float* Cf = (float*)Cv + (size_t)blockIdx.z * zstride;

  const int NT = Kc >> 6;
  const int srow = w * 8 + (lane >> 3);
  const int sch  = (lane & 7) ^ (lane >> 3);

  auto stageA = [&](int half, int tile) {
    const u16* src = A + (size_t)(m0 + half * 128 + srow) * lda + tile * 64 + sch * 8;
    u16* dst = &As[tile & 1][half * 128 + w * 8][0];
#pragma unroll
    for (int rnd = 0; rnd < 2; ++rnd)
      __builtin_amdgcn_global_load_lds(
          (const __attribute__((address_space(1))) void*)(src + (size_t)rnd * 64 * lda),
          (__attribute__((address_space(3))) void*)(dst + rnd * 64 * 64), 16, 0, 0);
  };
  auto stageB = [&](int half, int tile) {
    const u16* src = B + (size_t)(n0 + half * 128 + srow) * ldb + tile * 64 + sch * 8;
    u16* dst = &Bs[tile & 1][half * 128 + w * 8][0];
#pragma unroll
    for (int rnd = 0; rnd < 2; ++rnd)
      __builtin_amdgcn_global_load_lds(
          (const __attribute__((address_space(1))) void*)(src + (size_t)rnd * 64 * ldb),
          (__attribute__((address_space(3))) void*)(dst + rnd * 64 * 64), 16, 0, 0);
  };

  f32x4 acc[8][4] = {};
  bf16x8 a0[4][2], a1[4][2], b0[2][2], b1[2][2];

#define LOADAH(dstv, QR, base)                                                      \
  _Pragma("unroll") for (int m = 0; m < 4; ++m)                                     \
    _Pragma("unroll") for (int kh = 0; kh < 2; ++kh) {                              \
      int hr = wr * 128 + (QR) * 64 + m * 16 + l15;                                 \
      dstv[m][kh] = *(const bf16x8*)((base) + hr * 64 + ((((kh << 2) | g) ^ sl7) << 3)); \
    }
#define LOADBH(dstv, QC, base)                                                      \
  _Pragma("unroll") for (int n = 0; n < 2; ++n)                                     \
    _Pragma("unroll") for (int kh = 0; kh < 2; ++kh) {                              \
      int br = wc * 64 + (QC) * 32 + n * 16 + l15;                                  \
      dstv[n][kh] = *(const bf16x8*)((base) + br * 64 + ((((kh << 2) | g) ^ sl7) << 3)); \
    }
#define QMFMA(av, bv, QR, QC)                                                       \
  __builtin_amdgcn_s_setprio(1);                                                    \
  _Pragma("unroll") for (int m = 0; m < 4; ++m)                                     \
    _Pragma("unroll") for (int n = 0; n < 2; ++n)                                   \
      _Pragma("unroll") for (int kh = 0; kh < 2; ++kh)                              \
        acc[(QR) * 4 + m][(QC) * 2 + n] = MFMA16(av[m][kh], bv[n][kh],              \
                                                 acc[(QR) * 4 + m][(QC) * 2 + n]);  \
  __builtin_amdgcn_s_setprio(0);

  // prologue: tiles 0,1 fully staged; vmcnt(8) => tile0 arrived; preload A0,B0
  stageB(0, 0); stageB(1, 0); stageA(0, 0); stageA(1, 0);
  if (NT > 1) {
    stageB(0, 1); stageB(1, 1); stageA(0, 1); stageA(1, 1);
    asm volatile("s_waitcnt vmcnt(8)" ::: "memory");
  } else {
    asm volatile("s_waitcnt vmcnt(0)" ::: "memory");
  }
  __builtin_amdgcn_s_barrier();
  LOADAH(a0, 0, &As[0][0][0]);
  LOADBH(b0, 0, &Bs[0][0][0]);

  for (int t = 0; t < NT; ++t) {
    const u16* abase = &As[t & 1][0][0];
    const u16* bbase = &Bs[t & 1][0][0];
    // p1: read B1 early; compute Q00 (A0,B0)
    LOADBH(b1, 1, bbase);
    __builtin_amdgcn_s_barrier();
    QMFMA(a0, b0, 0, 0);
    __builtin_amdgcn_s_barrier();
    // p2: read A1 early; compute Q01 (A0,B1)
    LOADAH(a1, 1, abase);
    __builtin_amdgcn_s_barrier();
    QMFMA(a0, b1, 0, 1);
    __builtin_amdgcn_s_barrier();
    // p3: stage t+2 B (Bs[t&1] reads all complete); compute Q11 (A1,B1)
    if (t + 2 < NT) { stageB(0, t + 2); stageB(1, t + 2); }
    __builtin_amdgcn_s_barrier();
    QMFMA(a1, b1, 1, 1);
    __builtin_amdgcn_s_barrier();
    // p4: stage t+2 A; compute Q10 (A1,B0); boundary; preload next A0,B0
    if (t + 2 < NT) { stageA(0, t + 2); stageA(1, t + 2); }
    QMFMA(a1, b0, 1, 0);
    if (t + 1 < NT) {
      if (t + 2 < NT) asm volatile("s_waitcnt vmcnt(8)" ::: "memory");
      else            asm volatile("s_waitcnt vmcnt(0)" ::: "memory");
      __builtin_amdgcn_s_barrier();
      const u16* nab = &As[(t + 1) & 1][0][0];
      const u16* nbb = &Bs[(t + 1) & 1][0][0];
      LOADAH(a0, 0, nab);
      LOADBH(b0, 0, nbb);
    } else {
      __builtin_amdgcn_s_barrier();
    }
  }
#undef LOADAH
#undef LOADBH
#undef QMFMA

  const int er = g * 4;
#pragma unroll
  for (int i = 0; i < 8; ++i)
#pragma unroll
    for (int j = 0; j < 4; ++j)
#pragma unroll
      for (int r = 0; r < 4; ++r) {
        int row = m0 + wr * 128 + i * 16 + er + r;
        int col = n0 + wc * 64 + j * 16 + l15;
        if (OUTMODE == OUT_BF16) {
          ((u16*)Cv)[(size_t)row * ldc + col] = f2bf(acc[i][j][r]);
        } else if (OUTMODE == OUT_F32_ACC) {
          Cf[(size_t)row * ldc + col] += acc[i][j][r];
        } else {
          Cf[(size_t)row * ldc + col] = acc[i][j][r];
        }
      }
}

// ---------------- split-K reduce ----------------
__global__ __launch_bounds__(256) void k_red(const float* __restrict__ P,
                                             float* __restrict__ dst, int accmode) {
  size_t i = ((size_t)blockIdx.x * 256 + threadIdx.x) * 4;
  const size_t n = (size_t)4 * 1024 * 1024;
  float4 a = *(const float4*)(P + i);
  float4 b = *(const float4*)(P + n + i);
  float4 c = *(const float4*)(P + 2 * n + i);
  float4 d = *(const float4*)(P + 3 * n + i);
  float4 r;
  r.x = (a.x + b.x) + (c.x + d.x);
  r.y = (a.y + b.y) + (c.y + d.y);
  r.z = (a.z + b.z) + (c.z + d.z);
  r.w = (a.w + b.w) + (c.w + d.w);
  if (accmode) {
    float4 o = *(const float4*)(dst + i);
    r.x += o.x; r.y += o.y; r.z += o.z; r.w += o.w;
  }
  *(float4*)(dst + i) = r;
}

// ---------------- LoRA ----------------
__global__ __launch_bounds__(256) void k_lora_down(const u16* __restrict__ X,
                                                   const float* __restrict__ A,
                                                   float* __restrict__ T, int nproj) {
  int s = blockIdx.x;
  int lane = threadIdx.x & 63, wv = threadIdx.x >> 6;
  const u16* x = X + (size_t)s * D_;
  for (int p = wv; p < nproj * R_; p += 4) {
    const float* a = A + (size_t)p * D_;
    float sum = 0.f;
    for (int d = lane; d < D_; d += 64) sum += bf2f(x[d]) * a[d];
#pragma unroll
    for (int m = 1; m < 64; m <<= 1) sum += __shfl_xor(sum, m, 64);
    if (lane == 0) T[(size_t)s * (nproj * R_) + p] = sum;
  }
}

__global__ __launch_bounds__(256) void k_lora_up(float* __restrict__ Y, int ystride,
                                                 const float* __restrict__ T,
                                                 const float* __restrict__ Bm, int nproj) {
  int t = blockIdx.x * 256 + threadIdx.x;
  int d = t & (D_ - 1);
  int si = t >> 11;
  int i = si % nproj;
  int s = si / nproj;
  const float* tp = T + ((size_t)s * nproj + i) * R_;
  const float* bp = Bm + ((size_t)i * D_ + d) * R_;
  float acc = 0.f;
#pragma unroll
  for (int r = 0; r < R_; r++) acc += tp[r] * bp[r];
  Y[(size_t)s * ystride + (size_t)i * D_ + d] += 2.0f * acc;
}

// ---- LoRA-up fused into f32->bf16 convert for qkv: qkvb = bf16(qkv + lora) ----
__global__ __launch_bounds__(256) void k_lora_up_qkv(const float* __restrict__ qkv,
                                                     const float* __restrict__ T,
                                                     const float* __restrict__ Bm,
                                                     u16* __restrict__ qkvb) {
  size_t t = ((size_t)blockIdx.x * 256 + threadIdx.x) * 4;
  int c = (int)(t % 6144);
  int s = (int)(t / 6144);
  int i = c >> 11, d = c & 2047;
  const float* tp = T + ((size_t)s * 3 + i) * R_;
  float4 q = *(const float4*)(qkv + t);
  ushort4 o;
  float v[4] = {q.x, q.y, q.z, q.w};
#pragma unroll
  for (int j = 0; j < 4; ++j) {
    const float* bp = Bm + ((size_t)i * D_ + d + j) * R_;
    float acc = 0.f;
#pragma unroll
    for (int r = 0; r < R_; r++) acc += tp[r] * bp[r];
    v[j] += 2.0f * acc;
  }
  o.x = f2bf(v[0]); o.y = f2bf(v[1]); o.z = f2bf(v[2]); o.w = f2bf(v[3]);
  *(ushort4*)(qkvb + t) = o;
}

// ---- per-head V transpose: Vt[h][dh][s] = qkvb[s][4096 + h*128 + dh] ----
__global__ __launch_bounds__(256) void k_vtrans(const u16* __restrict__ qkvb,
                                                u16* __restrict__ Vt) {
  __shared__ u16 t[64][136];
  int s0 = blockIdx.x * 64, hh = blockIdx.y;
  int tid = threadIdx.x;
#pragma unroll
  for (int it = 0; it < 4; ++it) {
    int e = it * 2048 + tid * 8;
    int sr = e >> 7, sc = e & 127;
    *(uint4*)&t[sr][sc] =
        *(const uint4*)(qkvb + (size_t)(s0 + sr) * 6144 + 4096 + hh * 128 + sc);
  }
  __syncthreads();
#pragma unroll
  for (int it = 0; it < 4; ++it) {
    int q = it * 256 + tid;
    int dh = q >> 3, sc = (q & 7) * 8;
    u16 e0 = t[sc + 0][dh], e1 = t[sc + 1][dh], e2 = t[sc + 2][dh], e3 = t[sc + 3][dh];
    u16 e4 = t[sc + 4][dh], e5 = t[sc + 5][dh], e6 = t[sc + 6][dh], e7 = t[sc + 7][dh];
    uint4 o;
    o.x = (u32)e0 | ((u32)e1 << 16);
    o.y = (u32)e2 | ((u32)e3 << 16);
    o.z = (u32)e4 | ((u32)e5 << 16);
    o.w = (u32)e6 | ((u32)e7 << 16);
    *(uint4*)(Vt + ((size_t)hh * DH_ + dh) * S_ + s0 + sc) = o;
  }
}

// ======== MFMA flash attention v2 (unchanged) ========
__global__ __launch_bounds__(256) void k_attn2(const u16* __restrict__ qkvb,
                                               const u16* __restrict__ Vt,
                                               u16* __restrict__ out) {
  __shared__ u16 Ks[2][64 * 128];
  __shared__ u16 VTs[2][128 * 64];
  __shared__ u16 PT[4][64 * 16];
  const int tid = threadIdx.x;
  const int lane = tid & 63, w = tid >> 6;
  const int g = lane >> 4, l4 = lane & 15;
  const int p = blockIdx.x;
  const int hh = blockIdx.y;
  const int ld = 6144;
  const float rs = 0.08838834764831845f;
  const int qa0 = p * 64, qb0 = (31 - p) * 64;
  const int ntb = 32 - p;
  char* pt_w = (char*)&PT[w][0];

  const int qga = qa0 + w * 16 + l4;
  const int qgb = qb0 + w * 16 + l4;

  bf16x8 qfa[4], qfb[4];
#pragma unroll
  for (int kh = 0; kh < 4; ++kh) {
    qfa[kh] = *(const bf16x8*)(qkvb + (size_t)qga * ld + hh * DH_ + kh * 32 + g * 8);
    qfb[kh] = *(const bf16x8*)(qkvb + (size_t)qgb * ld + hh * DH_ + kh * 32 + g * 8);
  }

  float ma = -3.0e38f, la = 0.f, mb = -3.0e38f, lb = 0.f;
  f32x4 acc_a[8] = {}, acc_b[8] = {};
  bf16x8 pba[2], pbb[2];

  auto stage = [&](int buf, int kt) {
    const int kv0 = kt * 64;
#pragma unroll
    for (int i = 0; i < 4; ++i) {
      int rl = (w * 4 + i) * 4 + (lane >> 4);
      int cs = (lane & 15) ^ ((rl & 7) ^ (((rl >> 3) & 3) << 1));
      __builtin_amdgcn_global_load_lds(
          (const __attribute__((address_space(1))) void*)(
              qkvb + (size_t)(kv0 + rl) * ld + 2048 + hh * DH_ + cs * 8),
          (__attribute__((address_space(3))) void*)(&Ks[buf][(w * 4 + i) * 512]), 16, 0, 0);
    }
#pragma unroll
    for (int i = 0; i < 4; ++i) {
      int dh = (w * 4 + i) * 8 + (lane >> 3);
      int cs = (lane & 7) ^ (dh & 7);
      __builtin_amdgcn_global_load_lds(
          (const __attribute__((address_space(1))) void*)(
              Vt + ((size_t)hh * DH_ + dh) * S_ + kv0 + cs * 8),
          (__attribute__((address_space(3))) void*)(&VTs[buf][(w * 4 + i) * 512]), 16, 0, 0);
    }
  };

  auto softpb = [&](f32x4* sv, float& m, float& l, f32x4* acc, int qg, bool diag,
                    int kv0, bf16x8* pb) {
    float pv[16];
    float tmax = -3.0e38f;
#pragma unroll
    for (int kb = 0; kb < 4; ++kb)
#pragma unroll
      for (int r = 0; r < 4; ++r) {
        float s = sv[kb][r] * rs;
        if (diag) {
          int kglob = kv0 + kb * 16 + g * 4 + r;
          if (kglob > qg) s = -1.0e30f;
        }
        pv[kb * 4 + r] = s;
        tmax = fmaxf(tmax, s);
      }
    tmax = fmaxf(tmax, __shfl_xor(tmax, 16, 64));
    tmax = fmaxf(tmax, __shfl_xor(tmax, 32, 64));
    float mn = fmaxf(m, tmax);
    float corr = __expf(m - mn);
    m = mn;
    float ps = 0.f;
#pragma unroll
    for (int i = 0; i < 16; ++i) { pv[i] = __expf(pv[i] - mn); ps += pv[i]; }
    ps += __shfl_xor(ps, 16, 64);
    ps += __shfl_xor(ps, 32, 64);
    l = l * corr + ps;
#pragma unroll
    for (int f = 0; f < 8; ++f) {
      acc[f][0] *= corr; acc[f][1] *= corr; acc[f][2] *= corr; acc[f][3] *= corr;
    }
#pragma unroll
    for (int kb = 0; kb < 4; ++kb)
#pragma unroll
      for (int r = 0; r < 4; ++r) {
        int key = kb * 16 + g * 4 + r;
        int byte = (key * 32 + l4 * 2) ^ (((key >> 3) & 3) << 5);
        *(u16*)(pt_w + byte) = f2bf(pv[kb * 4 + r]);
      }
#pragma unroll
    for (int ks = 0; ks < 2; ++ks) {
      union { bf16x8 v; u16 s[8]; } ub;
#pragma unroll
      for (int j = 0; j < 8; ++j) {
        int key = ks * 32 + g * 8 + j;
        int byte = (key * 32 + l4 * 2) ^ (((key >> 3) & 3) << 5);
        ub.s[j] = *(const u16*)(pt_w + byte);
      }
      pb[ks] = ub.v;
    }
  };

  stage(0, 0);
  asm volatile("s_waitcnt vmcnt(0)" ::: "memory");
  __syncthreads();

  for (int kt = 0; kt < ntb; ++kt) {
    const int kv0 = kt * 64;
    const int buf = kt & 1;
    if (kt + 1 < ntb) stage(buf ^ 1, kt + 1);

    const char* kb_base = (const char*)&Ks[buf][0];
    const char* vb_base = (const char*)&VTs[buf][0];
    const bool doa = (kt <= p);

    f32x4 sa[4] = {}, sb[4] = {};
#pragma unroll
    for (int kb = 0; kb < 4; ++kb) {
#pragma unroll
      for (int kh = 0; kh < 4; ++kh) {
        int key = kb * 16 + l4;
        int ch = (kh * 4 + g) ^ ((key & 7) ^ (((key >> 3) & 3) << 1));
        bf16x8 af = *(const bf16x8*)(kb_base + key * 256 + ch * 16);
        if (doa) sa[kb] = MFMA16(af, qfa[kh], sa[kb]);
        sb[kb] = MFMA16(af, qfb[kh], sb[kb]);
      }
    }

    if (doa) softpb(sa, ma, la, acc_a, qga, kt == p, kv0, pba);
    softpb(sb, mb, lb, acc_b, qgb, kt == ntb - 1, kv0, pbb);

#pragma unroll
    for (int f = 0; f < 8; ++f) {
#pragma unroll
      for (int ks = 0; ks < 2; ++ks) {
        int dh = f * 16 + l4;
        int ch = (ks * 4 + g) ^ (dh & 7);
        bf16x8 va = *(const bf16x8*)(vb_base + dh * 128 + ch * 16);
        if (doa) acc_a[f] = MFMA16(va, pba[ks], acc_a[f]);
        acc_b[f] = MFMA16(va, pbb[ks], acc_b[f]);
      }
    }

    if (kt + 1 < ntb) {
      asm volatile("s_waitcnt vmcnt(0)" ::: "memory");
      __syncthreads();
    }
  }

  float inva = 1.f / la, invb = 1.f / lb;
  u16* opa = out + (size_t)qga * D_ + hh * DH_;
  u16* opb = out + (size_t)qgb * D_ + hh * DH_;
#pragma unroll
  for (int f = 0; f < 8; ++f)
#pragma unroll
    for (int r = 0; r < 4; ++r) {
      opa[f * 16 + g * 4 + r] = f2bf(acc_a[f][r] * inva);
      opb[f * 16 + g * 4 + r] = f2bf(acc_b[f][r] * invb);
    }
}

// ---------------- silu(gate)*up ----------------
__global__ __launch_bounds__(256) void k_silumul(u16* __restrict__ gu) {
  size_t i = ((size_t)blockIdx.x * 256 + threadIdx.x) * 4;
  int s = (int)(i >> 13);
  int f = (int)(i & 8191);
  u16* gp = gu + (size_t)s * (2 * DFF_) + f;
  ushort4 gt = *(ushort4*)gp;
  ushort4 up = *(ushort4*)(gp + DFF_);
  float g0 = bf2f(gt.x), g1 = bf2f(gt.y), g2 = bf2f(gt.z), g3 = bf2f(gt.w);
  float u0 = bf2f(up.x), u1 = bf2f(up.y), u2 = bf2f(up.z), u3 = bf2f(up.w);
  ushort4 o;
  o.x = f2bf(g0 / (1.f + __expf(-g0)) * u0);
  o.y = f2bf(g1 / (1.f + __expf(-g1)) * u1);
  o.z = f2bf(g2 / (1.f + __expf(-g2)) * u2);
  o.w = f2bf(g3 / (1.f + __expf(-g3)) * u3);
  *(ushort4*)gp = o;
}

// ---------------- gumbel softmax -> g (bf16) ----------------
__global__ __launch_bounds__(256) void k_gumbel(const float* __restrict__ logits,
                                                const float* __restrict__ u,
                                                u16* __restrict__ g) {
  int s = blockIdx.x;
  const float* lp = logits + (size_t)s * V_;
  const float* up = u + (size_t)s * V_;
  float m = -3.0e38f, l = 0.f;
  for (int v = threadIdx.x; v < V_; v += 256) {
    float z = lp[v] - __logf(-__logf(up[v] + 1e-10f) + 1e-10f);
    float mn = fmaxf(m, z);
    l = l * __expf(m - mn) + __expf(z - mn);
    m = mn;
  }
#pragma unroll
  for (int msk = 1; msk < 64; msk <<= 1) {
    float m2 = __shfl_xor(m, msk, 64), l2 = __shfl_xor(l, msk, 64);
    float mn = fmaxf(m, m2);
    l = l * __expf(m - mn) + l2 * __expf(m2 - mn);
    m = mn;
  }
  __shared__ float shm[4], shl[4];
  if ((threadIdx.x & 63) == 0) { shm[threadIdx.x >> 6] = m; shl[threadIdx.x >> 6] = l; }
  __syncthreads();
  float M = fmaxf(fmaxf(shm[0], shm[1]), fmaxf(shm[2], shm[3]));
  float L = shl[0] * __expf(shm[0] - M) + shl[1] * __expf(shm[1] - M) +
            shl[2] * __expf(shm[2] - M) + shl[3] * __expf(shm[3] - M);
  float inv = 1.f / L;
  u16* gp = g + (size_t)s * V_;
  for (int v = threadIdx.x; v < V_; v += 256) {
    float z = lp[v] - __logf(-__logf(up[v] + 1e-10f) + 1e-10f);
    gp[v] = f2bf(__expf(z - M) * inv);
  }
}

extern "C" void kernel_launch(void* const* d_in, const int* in_sizes, int n_in,
                              void* d_out, int out_size, void* d_ws, size_t ws_size,
                              hipStream_t stream) {
  const int*   ids        = (const int*)d_in[0];
  const float* u          = (const float*)d_in[1];
  const float* emb        = (const float*)d_in[2];
  const float* attn_scale = (const float*)d_in[3];
  const float* gu_scale   = (const float*)d_in[4];
  const float* dn_scale   = (const float*)d_in[5];
  const float* lora_A     = (const float*)d_in[6];
  const float* lora_B     = (const float*)d_in[7];
  const float* norm_w     = (const float*)d_in[8];
  const float* fnorm_w    = (const float*)d_in[9];
  const int*   attn_idx   = (const int*)d_in[10];
  const int*   gu_idx     = (const int*)d_in[11];
  const int*   dn_idx     = (const int*)d_in[12];

  float* out_se = (float*)d_out;
  float* out_lg = (float*)d_out + (size_t)S_ * D_;

  char* W = (char*)d_ws;
  float* h    = (float*)(W);                          // 16 MiB
  u16*   xb   = (u16*)(W + ((size_t)16 << 20));       // 8 MiB
  float* qkv  = (float*)(W + ((size_t)24 << 20));     // 48 MiB
  u16*   qkvb = (u16*)(W + ((size_t)72 << 20));       // 24 MiB
  u16*   Vtb  = (u16*)(W + ((size_t)96 << 20));       // 8 MiB
  u16*   ob   = (u16*)(W + ((size_t)104 << 20));      // 8 MiB
  u16*   gub  = (u16*)(W + ((size_t)112 << 20));      // 64 MiB
  u16*   wdq  = (u16*)(W + ((size_t)176 << 20));      // 64 MiB
  float* Tl   = (float*)(W + ((size_t)240 << 20));    // 192 KiB
  u16*   embb = (u16*)(W);                            // 125 MiB (head)
  u16*   gsm  = (u16*)(W + ((size_t)125 << 20));      // 125 MiB (head)
  u16*   embT = (u16*)(W);                            // 125 MiB (replaces embb)
  u16*   xbh  = (u16*)d_out;                          // final-norm out, parked in out_se
  float* Pk   = (float*)(W + ((size_t)250 << 20));    // 64 MiB split-K partials
  const bool big = ws_size >= ((size_t)314 << 20);
  const size_t ZS = (size_t)4 * 1024 * 1024;

  dim3 b256(256), b512(512);

  k_gather<<<dim3(S_ * D_ / 256), b256, 0, stream>>>(ids, emb, h);

  for (int l = 0; l < L_; ++l) {
    const int*   aidx = attn_idx + (size_t)l * 4 * D_ * D_;
    const float* ascl = attn_scale + (size_t)l * 4 * D_ * (D_ / 64);
    const float* lA   = lora_A + (size_t)l * 4 * R_ * D_;
    const float* lB   = lora_B + (size_t)l * 4 * D_ * R_;

    // ---- attention ----
    k_rmsnorm<<<dim3(S_), b256, 0, stream>>>(h, norm_w + (size_t)l * 2 * D_, xb);
    k_dequant<<<dim3(4 * D_ * D_ / 8 / 256), b256, 0, stream>>>(aidx, ascl, wdq, 11);
    k_gemm256<OUT_F32><<<dim3(3 * D_ / 256, 8), b512, 0, stream>>>(
        xb, D_, wdq, D_, qkv, 3 * D_, D_, 0);
    k_lora_down<<<dim3(S_), b256, 0, stream>>>(xb, lA, Tl, 3);
    k_lora_up_qkv<<<dim3(S_ * 3 * D_ / 4 / 256), b256, 0, stream>>>(qkv, Tl, lB, qkvb);
    k_vtrans<<<dim3(S_ / 64, H_), b256, 0, stream>>>(qkvb, Vtb);
    k_attn2<<<dim3(16, H_), b256, 0, stream>>>(qkvb, Vtb, ob);
    k_gemm256<OUT_F32_ACC><<<dim3(D_ / 256, 8), b512, 0, stream>>>(
        ob, D_, wdq + (size_t)3 * D_ * D_, D_, h, D_, D_, 0);
    k_lora_down<<<dim3(S_), b256, 0, stream>>>(ob, lA + (size_t)3 * R_ * D_, Tl, 1);
    k_lora_up<<<dim3(S_ * D_ / 256), b256, 0, stream>>>(h, D_, Tl, lB + (size_t)3 * D_ * R_, 1);

    // ---- ffn ----
    k_rmsnorm<<<dim3(S_), b256, 0, stream>>>(h, norm_w + (size_t)l * 2 * D_ + D_, xb);
    k_dequant<<<dim3(2 * DFF_ * D_ / 8 / 256), b256, 0, stream>>>(
        gu_idx + (size_t)l * 2 * DFF_ * D_, gu_scale + (size_t)l * 2 * DFF_ * (D_ / 64), wdq, 11);
    k_gemm256<OUT_BF16><<<dim3(2 * DFF_ / 256, 8), b512, 0, stream>>>(
        xb, D_, wdq, D_, gub, 2 * DFF_, D_, 0);
    k_silumul<<<dim3(S_ * DFF_ / 4 / 256), b256, 0, stream>>>(gub);
    k_dequant<<<dim3(D_ * DFF_ / 8 / 256), b256, 0, stream>>>(
        dn_idx + (size_t)l * D_ * DFF_, dn_scale + (size_t)l * D_ * (DFF_ / 64), wdq, 13);
    if (big) {
      k_gemm256<OUT_F32><<<dim3(D_ / 256, 8, 4), b512, 0, stream>>>(
          gub, 2 * DFF_, wdq, DFF_, Pk, D_, DFF_ / 4, ZS);
      k_red<<<dim3(4096), b256, 0, stream>>>(Pk, h, 1);
    } else {
      k_gemm256<OUT_F32_ACC><<<dim3(D_ / 256, 8), b512, 0, stream>>>(
          gub, 2 * DFF_, wdq, DFF_, h, D_, DFF_, 0);
    }
  }

  // ---- head ----
  k_rmsnorm<<<dim3(S_), b256, 0, stream>>>(h, fnorm_w, xbh);
  k_f2b<<<dim3(V_ * D_ / 8 / 256), b256, 0, stream>>>(emb, embb);
  k_gemm256<OUT_F32><<<dim3(V_ / 256, 8), b512, 0, stream>>>(
      xbh, D_, embb, D_, out_lg, V_, D_, 0);
  k_gumbel<<<dim3(S_), b256, 0, stream>>>(out_lg, u, gsm);
  k_transpose<<<dim3(V_ / 64, D_ / 64), b256, 0, stream>>>(emb, embT);
  if (big) {
    k_gemm256<OUT_F32><<<dim3(D_ / 256, 8, 4), b512, 0, stream>>>(
        gsm, V_, embT, V_, Pk, D_, V_ / 4, ZS);
    k_red<<<dim3(4096), b256, 0, stream>>>(Pk, out_se, 0);
  } else {
    k_gemm256<OUT_F32><<<dim3(D_ / 256, 8), b512, 0, stream>>>(
        gsm, V_, embT, V_, out_se, D_, V_, 0);
  }
}